// Round 5
// baseline (75.768 us; speedup 1.0000x reference)
//
#include <hip/hip_runtime.h>
#include <math.h>
#include <float.h>

#define BB 256
#define NN 400
#define DD 512
#define KK 20

__device__ __forceinline__ float dot8(float4 a0, float4 a1, float4 b0, float4 b1) {
    return a0.x*b0.x + a0.y*b0.y + a0.z*b0.z + a0.w*b0.w
         + a1.x*b1.x + a1.y*b1.y + a1.z*b1.z + a1.w*b1.w;
}

// ---- Kernel 1: scorer = tanh(W h + b). Tiled for W reuse (verified round 4).
__global__ __launch_bounds__(1024) void scorer_kernel(
    const float* __restrict__ h_t,   // [B, D]
    const float* __restrict__ W,     // [D, D]
    const float* __restrict__ bmap,  // [D]
    float* __restrict__ out2)        // [B, D] scorer (output 2)
{
    const int blk = blockIdx.x;
    const int dc = blk & 15, bg = blk >> 4;
    const int wave = threadIdx.x >> 6, lane = threadIdx.x & 63;

    const int d0 = dc * 32 + wave * 2;
    const int d1 = d0 + 1;
    const float4* wp0 = (const float4*)(W + (size_t)d0 * DD);
    const float4* wp1 = (const float4*)(W + (size_t)d1 * DD);
    const float4 w00 = wp0[lane], w01 = wp0[lane + 64];
    const float4 w10 = wp1[lane], w11 = wp1[lane + 64];
    const float bias0 = bmap[d0], bias1 = bmap[d1];

    #pragma unroll 4
    for (int bi = 0; bi < 32; ++bi) {
        const int b = bg * 32 + bi;
        const float4* hp = (const float4*)(h_t + (size_t)b * DD);
        float4 hb0 = hp[lane], hb1 = hp[lane + 64];
        float p0 = dot8(w00, w01, hb0, hb1);
        float p1 = dot8(w10, w11, hb0, hb1);
        #pragma unroll
        for (int off = 32; off; off >>= 1) {
            p0 += __shfl_xor(p0, off, 64);
            p1 += __shfl_xor(p1, off, 64);
        }
        if (lane == 0) {
            out2[(size_t)b * DD + d0] = tanhf(p0 + bias0);
            out2[(size_t)b * DD + d1] = tanhf(p1 + bias1);
        }
    }
}

// ---- Kernel 2: pure-streaming raw scores. 1024 blocks x 256 threads.
// block = (b = blk>>2, quarter = blk&3); wave handles 25 consecutive rows.
__global__ __launch_bounds__(256, 4) void scores_kernel(
    const float* __restrict__ embs,    // [B, N, D]
    const float* __restrict__ scorer,  // [B, D]
    float* __restrict__ raw)           // [B, N] unnormalized scores (ws)
{
    const int blk = blockIdx.x;
    const int b = blk >> 2, q = blk & 3;
    const int wave = threadIdx.x >> 6, lane = threadIdx.x & 63;

    const float4* sp = (const float4*)(scorer + (size_t)b * DD);
    const float4 g0 = sp[lane];
    const float4 g1 = sp[lane + 64];

    const int n0 = q * 100 + wave * 25;
    const float* base = embs + ((size_t)b * NN + n0) * DD;

    #pragma unroll
    for (int g = 0; g < 5; ++g) {
        float4 A0[5], A1[5];
        #pragma unroll
        for (int r = 0; r < 5; ++r) {
            const float4* p = (const float4*)(base + (size_t)(g * 5 + r) * DD);
            A0[r] = p[lane];
            A1[r] = p[lane + 64];
        }
        float s0 = dot8(A0[0], A1[0], g0, g1);
        float s1 = dot8(A0[1], A1[1], g0, g1);
        float s2 = dot8(A0[2], A1[2], g0, g1);
        float s3 = dot8(A0[3], A1[3], g0, g1);
        float s4 = dot8(A0[4], A1[4], g0, g1);
        #pragma unroll
        for (int off = 32; off; off >>= 1) {
            s0 += __shfl_xor(s0, off, 64);
            s1 += __shfl_xor(s1, off, 64);
            s2 += __shfl_xor(s2, off, 64);
            s3 += __shfl_xor(s3, off, 64);
            s4 += __shfl_xor(s4, off, 64);
        }
        if (lane == 0) {
            float* o = raw + (size_t)b * NN + n0 + g * 5;
            o[0] = s0; o[1] = s1; o[2] = s2; o[3] = s3; o[4] = s4;
        }
    }
}

// ---- Kernel 3: per-batch finalize. 256 blocks x 512 threads (8 waves).
__global__ __launch_bounds__(512) void finalize_kernel(
    const float* __restrict__ embs,    // [B, N, D]
    const float* __restrict__ scorer,  // [B, D] (= out2)
    const float* __restrict__ raw,     // [B, N]
    float* __restrict__ out0,          // [B, K, K]
    float* __restrict__ out1,          // [B]
    float* __restrict__ out3,          // [B] entropy
    float* __restrict__ out4)          // [B, K] indices as float
{
    const int b = blockIdx.x;
    const int t = threadIdx.x;
    const int wave = t >> 6, lane = t & 63;

    __shared__ float sh_s[NN];
    __shared__ float redf[8], redf2[8];
    __shared__ float mZ[3];          // inv_norm, m, logZ
    __shared__ int   sh_topk[KK];
    __shared__ float sh_th[KK];

    // inv_norm from scorer row (all 512 threads)
    {
        float v = scorer[(size_t)b * DD + t];
        float ss = v * v;
        #pragma unroll
        for (int off = 32; off; off >>= 1) ss += __shfl_xor(ss, off, 64);
        if (lane == 0) redf[wave] = ss;
    }
    const float rawv = (t < NN) ? raw[(size_t)b * NN + t] : 0.f;
    __syncthreads();
    if (t == 0) {
        float tot = 0.f;
        #pragma unroll
        for (int i = 0; i < 8; ++i) tot += redf[i];
        mZ[0] = 1.0f / sqrtf(tot);
    }
    __syncthreads();
    const float inv = mZ[0];

    const float x = (t < NN) ? rawv * inv : -FLT_MAX;
    if (t < NN) sh_s[t] = x;

    // block max
    {
        float m = x;
        #pragma unroll
        for (int off = 32; off; off >>= 1) m = fmaxf(m, __shfl_xor(m, off, 64));
        if (lane == 0) redf[wave] = m;
    }
    __syncthreads();
    if (t == 0) {
        float m = redf[0];
        #pragma unroll
        for (int i = 1; i < 8; ++i) m = fmaxf(m, redf[i]);
        mZ[1] = m;
    }
    __syncthreads();
    const float m = mZ[1];

    // Z and entropy sums
    {
        float e = 0.f, wv = 0.f;
        if (t < NN) {
            float d = x - m;
            e = expf(d);
            wv = e * d;
        }
        #pragma unroll
        for (int off = 32; off; off >>= 1) {
            e  += __shfl_xor(e, off, 64);
            wv += __shfl_xor(wv, off, 64);
        }
        if (lane == 0) { redf[wave] = e; redf2[wave] = wv; }
    }
    __syncthreads();
    if (t == 0) {
        float Z = 0.f, Ws = 0.f;
        #pragma unroll
        for (int i = 0; i < 8; ++i) { Z += redf[i]; Ws += redf2[i]; }
        float logZ = logf(Z);
        mZ[2] = logZ;
        out3[b] = logZ - Ws / Z;
    }
    __syncthreads();
    const float logZ = mZ[2];

    // top-K on wave 0, fully in-register
    if (wave == 0) {
        float v0 = sh_s[lane      ];
        float v1 = sh_s[lane +  64];
        float v2 = sh_s[lane + 128];
        float v3 = sh_s[lane + 192];
        float v4 = sh_s[lane + 256];
        float v5 = sh_s[lane + 320];
        float v6 = (lane + 384 < NN) ? sh_s[lane + 384] : -FLT_MAX;
        float acc = 0.f;
        for (int k = 0; k < KK; ++k) {
            float bv = v0; int bi = lane;
            if (v1 > bv) { bv = v1; bi = lane + 64; }
            if (v2 > bv) { bv = v2; bi = lane + 128; }
            if (v3 > bv) { bv = v3; bi = lane + 192; }
            if (v4 > bv) { bv = v4; bi = lane + 256; }
            if (v5 > bv) { bv = v5; bi = lane + 320; }
            if (v6 > bv) { bv = v6; bi = lane + 384; }
            #pragma unroll
            for (int off = 32; off; off >>= 1) {
                float ov = __shfl_xor(bv, off, 64);
                int   oi = __shfl_xor(bi, off, 64);
                if (ov > bv || (ov == bv && oi < bi)) { bv = ov; bi = oi; }
            }
            if (lane == 0) {
                sh_topk[k] = bi;
                sh_th[k] = tanhf(bv);
                out4[(size_t)b * KK + k] = (float)bi;
                acc += bv - m - logZ;
            }
            v0 = (bi == lane      ) ? -FLT_MAX : v0;
            v1 = (bi == lane +  64) ? -FLT_MAX : v1;
            v2 = (bi == lane + 128) ? -FLT_MAX : v2;
            v3 = (bi == lane + 192) ? -FLT_MAX : v3;
            v4 = (bi == lane + 256) ? -FLT_MAX : v4;
            v5 = (bi == lane + 320) ? -FLT_MAX : v5;
            v6 = (bi == lane + 384) ? -FLT_MAX : v6;
        }
        if (lane == 0) out1[b] = acc / (float)KK;
    }
    __syncthreads();

    // out0[b, j, k] = embs[b, topk[k], j] * th[k]
    if (t < NN) {
        int k = t / KK;
        int j = t - k * KK;
        float val = embs[((size_t)b * NN + sh_topk[k]) * DD + j] * sh_th[k];
        out0[(size_t)b * (KK * KK) + j * KK + k] = val;
    }
}

extern "C" void kernel_launch(void* const* d_in, const int* in_sizes, int n_in,
                              void* d_out, int out_size, void* d_ws, size_t ws_size,
                              hipStream_t stream) {
    const float* node_embs = (const float*)d_in[0];
    // d_in[1] = mask, unused
    const float* h_t   = (const float*)d_in[2];
    const float* W_map = (const float*)d_in[3];
    const float* b_map = (const float*)d_in[4];
    (void)in_sizes; (void)n_in; (void)out_size; (void)ws_size;

    float* ob = (float*)d_out;
    float* out0 = ob;                       // [B,K,K] -> 102400
    float* out1 = ob + 102400;              // [B]     -> 256
    float* out2 = ob + 102656;              // [B,D]   -> 131072
    float* out3 = ob + 233728;              // [B]     -> 256
    float* out4 = ob + 233984;              // [B,K]   -> 5120

    float* raw_scores = (float*)d_ws;       // B*N = 102400 floats

    scorer_kernel<<<128, 1024, 0, stream>>>(h_t, W_map, b_map, out2);
    scores_kernel<<<BB * 4, 256, 0, stream>>>(node_embs, out2, raw_scores);
    finalize_kernel<<<BB, 512, 0, stream>>>(node_embs, out2, raw_scores,
                                            out0, out1, out3, out4);
}

// Round 6
// 73.450 us; speedup vs baseline: 1.0316x; 1.0316x over previous
//
#include <hip/hip_runtime.h>
#include <math.h>
#include <float.h>

#define BB 256
#define NN 400
#define DD 512
#define KK 20

__device__ __forceinline__ float dot8(float4 a0, float4 a1, float4 b0, float4 b1) {
    return a0.x*b0.x + a0.y*b0.y + a0.z*b0.z + a0.w*b0.w
         + a1.x*b1.x + a1.y*b1.y + a1.z*b1.z + a1.w*b1.w;
}

// ---- Kernel 1: scorer = tanh(W h + b). W-tiled GEMV (verified r4/r5).
// grid = 128: dc = blk&15 (32 d-rows), bg = blk>>4 (32 batches).
__global__ __launch_bounds__(1024) void scorer_kernel(
    const float* __restrict__ h_t,   // [B, D]
    const float* __restrict__ W,     // [D, D]
    const float* __restrict__ bmap,  // [D]
    float* __restrict__ out2)        // [B, D] scorer (output 2)
{
    const int blk = blockIdx.x;
    const int dc = blk & 15, bg = blk >> 4;
    const int wave = threadIdx.x >> 6, lane = threadIdx.x & 63;

    const int d0 = dc * 32 + wave * 2;
    const int d1 = d0 + 1;
    const float4* wp0 = (const float4*)(W + (size_t)d0 * DD);
    const float4* wp1 = (const float4*)(W + (size_t)d1 * DD);
    const float4 w00 = wp0[lane], w01 = wp0[lane + 64];
    const float4 w10 = wp1[lane], w11 = wp1[lane + 64];
    const float bias0 = bmap[d0], bias1 = bmap[d1];

    #pragma unroll 4
    for (int bi = 0; bi < 32; ++bi) {
        const int b = bg * 32 + bi;
        const float4* hp = (const float4*)(h_t + (size_t)b * DD);
        float4 hb0 = hp[lane], hb1 = hp[lane + 64];
        float p0 = dot8(w00, w01, hb0, hb1);
        float p1 = dot8(w10, w11, hb0, hb1);
        #pragma unroll
        for (int off = 32; off; off >>= 1) {
            p0 += __shfl_xor(p0, off, 64);
            p1 += __shfl_xor(p1, off, 64);
        }
        if (lane == 0) {
            out2[(size_t)b * DD + d0] = tanhf(p0 + bias0);
            out2[(size_t)b * DD + d1] = tanhf(p1 + bias1);
        }
    }
}

// ---- Kernel 2: fused scores + stats + topk + outputs. One block per batch,
// 16 waves; stream phase software-pipelined (ping-pong 5-row groups).
__global__ __launch_bounds__(1024, 4) void fused_topk_kernel(
    const float* __restrict__ embs,    // [B, N, D]
    const float* __restrict__ scorer,  // [B, D] (= out2)
    float* __restrict__ out0,          // [B, K, K]
    float* __restrict__ out1,          // [B]
    float* __restrict__ out3,          // [B] entropy
    float* __restrict__ out4)          // [B, K] indices as float
{
    const int b = blockIdx.x;
    const int t = threadIdx.x;
    const int wave = t >> 6, lane = t & 63;

    __shared__ float sh_sc[DD];
    __shared__ float sh_s[NN];
    __shared__ float redf[16], redf2[16], redq[8];
    __shared__ float mZ[3];          // inv_norm, m, logZ
    __shared__ int   sh_topk[KK];
    __shared__ float sh_th[KK];

    // stage scorer row + start sum-of-squares (waves 0..7 cover 512)
    if (t < DD) {
        float v = scorer[(size_t)b * DD + t];
        sh_sc[t] = v;
        float ss = v * v;
        #pragma unroll
        for (int off = 32; off; off >>= 1) ss += __shfl_xor(ss, off, 64);
        if (lane == 0) redq[wave] = ss;
    }
    __syncthreads();

    const float4 g0 = ((const float4*)sh_sc)[lane];
    const float4 g1 = ((const float4*)sh_sc)[lane + 64];

    // ---- stream phase: wave w -> rows [25w, 25w+25), ping-pong 5-row groups ----
    {
        const int n0 = wave * 25;
        const float* base = embs + ((size_t)b * NN + n0) * DD;

        float4 A0[5], A1[5], B0[5], B1[5];
        #pragma unroll
        for (int r = 0; r < 5; ++r) {
            const float4* p = (const float4*)(base + (size_t)r * DD);
            A0[r] = p[lane]; A1[r] = p[lane + 64];
        }
        #pragma unroll
        for (int g = 0; g < 5; ++g) {
            if (g < 4) {
                #pragma unroll
                for (int r = 0; r < 5; ++r) {
                    const float4* p = (const float4*)(base + (size_t)((g + 1) * 5 + r) * DD);
                    B0[r] = p[lane]; B1[r] = p[lane + 64];
                }
            }
            float s[5];
            #pragma unroll
            for (int r = 0; r < 5; ++r) s[r] = dot8(A0[r], A1[r], g0, g1);
            #pragma unroll
            for (int off = 32; off; off >>= 1) {
                #pragma unroll
                for (int r = 0; r < 5; ++r) s[r] += __shfl_xor(s[r], off, 64);
            }
            if (lane == 0) {
                float* o = sh_s + n0 + g * 5;
                #pragma unroll
                for (int r = 0; r < 5; ++r) o[r] = s[r];
            }
            if (g < 4) {
                #pragma unroll
                for (int r = 0; r < 5; ++r) { A0[r] = B0[r]; A1[r] = B1[r]; }
            }
        }
    }
    __syncthreads();

    if (t == 0) {
        float tot = 0.f;
        #pragma unroll
        for (int i = 0; i < 8; ++i) tot += redq[i];
        mZ[0] = 1.0f / sqrtf(tot);
    }
    __syncthreads();
    const float inv = mZ[0];

    // ---- block max of scaled scores ----
    const float x = (t < NN) ? sh_s[t] * inv : -FLT_MAX;
    {
        float m = x;
        #pragma unroll
        for (int off = 32; off; off >>= 1) m = fmaxf(m, __shfl_xor(m, off, 64));
        if (lane == 0) redf[wave] = m;
    }
    __syncthreads();
    if (t == 0) {
        float m = redf[0];
        #pragma unroll
        for (int i = 1; i < 16; ++i) m = fmaxf(m, redf[i]);
        mZ[1] = m;
    }
    __syncthreads();
    const float m = mZ[1];

    // ---- Z and entropy sums ----
    {
        float e = 0.f, wv = 0.f;
        if (t < NN) {
            float d = x - m;
            e = expf(d);
            wv = e * d;
        }
        #pragma unroll
        for (int off = 32; off; off >>= 1) {
            e  += __shfl_xor(e, off, 64);
            wv += __shfl_xor(wv, off, 64);
        }
        if (lane == 0) { redf[wave] = e; redf2[wave] = wv; }
    }
    __syncthreads();
    if (t == 0) {
        float Z = 0.f, Ws = 0.f;
        #pragma unroll
        for (int i = 0; i < 16; ++i) { Z += redf[i]; Ws += redf2[i]; }
        float logZ = logf(Z);
        mZ[2] = logZ;
        out3[b] = logZ - Ws / Z;
    }
    __syncthreads();
    const float logZ = mZ[2];

    // ---- top-K on wave 0, fully in-register ----
    if (wave == 0) {
        float v0 = sh_s[lane      ] * inv;
        float v1 = sh_s[lane +  64] * inv;
        float v2 = sh_s[lane + 128] * inv;
        float v3 = sh_s[lane + 192] * inv;
        float v4 = sh_s[lane + 256] * inv;
        float v5 = sh_s[lane + 320] * inv;
        float v6 = (lane + 384 < NN) ? sh_s[lane + 384] * inv : -FLT_MAX;
        float acc = 0.f;
        for (int k = 0; k < KK; ++k) {
            float bv = v0; int bi = lane;
            if (v1 > bv) { bv = v1; bi = lane + 64; }
            if (v2 > bv) { bv = v2; bi = lane + 128; }
            if (v3 > bv) { bv = v3; bi = lane + 192; }
            if (v4 > bv) { bv = v4; bi = lane + 256; }
            if (v5 > bv) { bv = v5; bi = lane + 320; }
            if (v6 > bv) { bv = v6; bi = lane + 384; }
            #pragma unroll
            for (int off = 32; off; off >>= 1) {
                float ov = __shfl_xor(bv, off, 64);
                int   oi = __shfl_xor(bi, off, 64);
                if (ov > bv || (ov == bv && oi < bi)) { bv = ov; bi = oi; }
            }
            if (lane == 0) {
                sh_topk[k] = bi;
                sh_th[k] = tanhf(bv);
                out4[(size_t)b * KK + k] = (float)bi;
                acc += bv - m - logZ;
            }
            v0 = (bi == lane      ) ? -FLT_MAX : v0;
            v1 = (bi == lane +  64) ? -FLT_MAX : v1;
            v2 = (bi == lane + 128) ? -FLT_MAX : v2;
            v3 = (bi == lane + 192) ? -FLT_MAX : v3;
            v4 = (bi == lane + 256) ? -FLT_MAX : v4;
            v5 = (bi == lane + 320) ? -FLT_MAX : v5;
            v6 = (bi == lane + 384) ? -FLT_MAX : v6;
        }
        if (lane == 0) out1[b] = acc / (float)KK;
    }
    __syncthreads();

    // ---- out0[b, j, k] = embs[b, topk[k], j] * th[k] ----
    if (t < NN) {
        int k = t / KK;
        int j = t - k * KK;
        float val = embs[((size_t)b * NN + sh_topk[k]) * DD + j] * sh_th[k];
        out0[(size_t)b * (KK * KK) + j * KK + k] = val;
    }
}

extern "C" void kernel_launch(void* const* d_in, const int* in_sizes, int n_in,
                              void* d_out, int out_size, void* d_ws, size_t ws_size,
                              hipStream_t stream) {
    const float* node_embs = (const float*)d_in[0];
    // d_in[1] = mask, unused
    const float* h_t   = (const float*)d_in[2];
    const float* W_map = (const float*)d_in[3];
    const float* b_map = (const float*)d_in[4];
    (void)in_sizes; (void)n_in; (void)out_size; (void)d_ws; (void)ws_size;

    float* ob = (float*)d_out;
    float* out0 = ob;                       // [B,K,K] -> 102400
    float* out1 = ob + 102400;              // [B]     -> 256
    float* out2 = ob + 102656;              // [B,D]   -> 131072
    float* out3 = ob + 233728;              // [B]     -> 256
    float* out4 = ob + 233984;              // [B,K]   -> 5120

    scorer_kernel<<<128, 1024, 0, stream>>>(h_t, W_map, b_map, out2);
    fused_topk_kernel<<<BB, 1024, 0, stream>>>(node_embs, out2,
                                               out0, out1, out3, out4);
}